// Round 9
// baseline (42.451 us; speedup 1.0000x reference)
//
#include <hip/hip_runtime.h>

// YOLO loss on (B,7,7,30) fp32 pred/target -> scalar.
// R9 = R7 (4 lanes/cell, single-pass coalesced, 4 shuffles/chunk, divergent
// coord on 16/64 lanes) + __builtin_nontemporal_load on all tensor reads
// (nt flag: bypass L1 allocation; zero reuse stream, L1 is pure churn).
// Plateau context: R2/R4/R7/R8 all 36-38us = 8.7 B/cy/CU vs 10.2 copy
// ceiling; L3-resident replays equal-speed => CU-side service path bound.

#define NC 30

typedef float f4 __attribute__((ext_vector_type(4), aligned(4)));

__device__ __forceinline__ float sq(float x) { return x * x; }

__device__ __forceinline__ void make_box(float cx, float cy, float w, float h,
                                         float jf, float kf, float b[4]) {
    float x = (cx + jf) * (1.0f / 7.0f);
    float y = (cy + kf) * (1.0f / 7.0f);
    b[0] = x - w * 0.5f;
    b[1] = y - h * 0.5f;
    b[2] = x + w * 0.5f;
    b[3] = y + h * 0.5f;
}

__device__ __forceinline__ float iou(const float a[4], const float b[4]) {
    float ix1 = fmaxf(a[0], b[0]);
    float iy1 = fmaxf(a[1], b[1]);
    float ix2 = fminf(a[2], b[2]);
    float iy2 = fminf(a[3], b[3]);
    float iw = fmaxf(ix2 - ix1, 0.0f);
    float ih = fmaxf(iy2 - iy1, 0.0f);
    float inter = iw * ih;
    float area_a = (a[2] - a[0]) * (a[3] - a[1]);
    float area_b = (b[2] - b[0]) * (b[3] - b[1]);
    return inter > 0.0f ? inter / (area_a + area_b - inter) : 0.0f;
}

__device__ __forceinline__ f4 ntload(const float* p) {
    return __builtin_nontemporal_load(reinterpret_cast<const f4*>(p));
}

template <bool USE_WS>
__global__ __launch_bounds__(256) void yolo_partial_kernel(
    const float* __restrict__ pred, const float* __restrict__ targ,
    float* __restrict__ dst, int ncells, float scale) {
    int t = threadIdx.x;
    int q = t & 3;        // lane within 4-lane cell-group
    int gbase = t & ~3;   // group leader
    int nchunks = (ncells + 63) / 64;  // 64 cells per block-iteration
    int total_dw = ncells * NC;

    float acc = 0.0f;

    for (int chunk = blockIdx.x; chunk < nchunks; chunk += gridDim.x) {
        int cell = chunk * 64 + (t >> 2);
        bool ok = cell < ncells;

        // lane q owns dwords [cell*30 + 8q, +8) of both tensors
        int dwbase = cell * NC + 8 * q;
        int ldbase = dwbase;
        int shift = 0;
        if (ok && dwbase + 8 > total_dw) {  // only the global last lane
            ldbase = total_dw - 8;
            shift = dwbase - ldbase;  // == 2
        }

        f4 Pa = {0.f, 0.f, 0.f, 0.f}, Pb = {0.f, 0.f, 0.f, 0.f};
        f4 Ta = {0.f, 0.f, 0.f, 0.f}, Tb = {0.f, 0.f, 0.f, 0.f};
        if (ok) {
            Pa = ntload(pred + ldbase);
            Pb = ntload(pred + ldbase + 4);
            Ta = ntload(targ + ldbase);
            Tb = ntload(targ + ldbase + 4);
        }
        if (shift) {  // remap loaded -> nominal channel positions (shift==2)
            f4 p0 = Pa, p1 = Pb, u0 = Ta, u1 = Tb;
            Pa[0] = p0[2]; Pa[1] = p0[3]; Pa[2] = p1[0]; Pa[3] = p1[1];
            Pb[0] = p1[2]; Pb[1] = p1[3]; Pb[2] = 0.f;   Pb[3] = 0.f;
            Ta[0] = u0[2]; Ta[1] = u0[3]; Ta[2] = u1[0]; Ta[3] = u1[1];
            Tb[0] = u1[2]; Tb[1] = u1[3]; Tb[2] = 0.f;   Tb[3] = 0.f;
        }

        // obj mask: T4 lives in group-leader's Tb[0]
        float t4 = __shfl(Tb[0], gbase, 64);
        float objw = t4 > 0.0f ? 1.0f : 0.0f;

        // cls partial fully in-lane: ch = 8q + e (Pa: e=0..3, Pb: e=4..7)
        float cls = 0.0f;
#pragma unroll
        for (int e = 0; e < 4; ++e) {
            int ch = 8 * q + e;
            float d = Pa[e] - Ta[e];
            cls += (ch >= 10 && ch < NC) ? d * d : 0.0f;
        }
#pragma unroll
        for (int e = 0; e < 4; ++e) {
            int ch = 8 * q + 4 + e;
            float d = Pb[e] - Tb[e];
            cls += (ch >= 10 && ch < NC) ? d * d : 0.0f;
        }
        acc += objw * cls;

        // gather for coord: lane q=1 holds d8..11 in its Pa/Ta
        float P8 = __shfl(Pa[0], gbase + 1, 64);
        float P9 = __shfl(Pa[1], gbase + 1, 64);
        float T8 = __shfl(Ta[0], gbase + 1, 64);  // T9 unused by reference

        if (q == 0 && ok) {
            // local: P0..3=Pa, P4..7=Pb, T0..3=Ta, T4..7=Tb
            int q7 = cell / 7;
            float kf = (float)(cell - q7 * 7);
            float jf = (float)(q7 % 7);

            float b1[4], b2[4], tbx[4];
            make_box(Pa[0], Pa[1], Pa[2], Pa[3], jf, kf, b1);
            make_box(Pb[1], Pb[2], Pb[3], P8, jf, kf, b2);
            make_box(Ta[0], Ta[1], Ta[2], Ta[3], jf, kf, tbx);

            float i1 = iou(b1, tbx);
            float i2 = iou(b2, tbx);

            bool obj = Tb[0] > 0.0f;
            bool pick1 = i1 >= i2;

            float coo1 = 5.0f * (sq(Pa[0] - Ta[0]) + sq(Pa[1] - Ta[1]) +
                                 sq(sqrtf(Pa[2]) - sqrtf(Ta[2])) +
                                 sq(sqrtf(Pa[3]) - sqrtf(Ta[3]))) +
                         sq(Pb[0] - i1);
            float non1 = 0.5f * sq(Pb[0] - i2);

            float coo2 = 5.0f * (sq(Pb[1] - Tb[1]) + sq(Pb[2] - Tb[2]) +
                                 sq(sqrtf(Pb[3]) - sqrtf(Tb[3])) +
                                 sq(sqrtf(P8) - sqrtf(T8))) +
                         sq(P9 - i2);
            float non2 = 0.5f * sq(P9 - i1);

            float noobj = 0.5f * (Pb[0] * Pb[0] + P9 * P9);

            float resp = pick1 ? (coo1 + non1) : (coo2 + non2);
            acc += obj ? resp : noobj;
        }
    }

    // block reduction, one plain store per block
#pragma unroll
    for (int off = 32; off > 0; off >>= 1) acc += __shfl_down(acc, off);

    __shared__ float wsum[4];
    int wave = t >> 6;
    int lane = t & 63;
    if (lane == 0) wsum[wave] = acc;
    __syncthreads();

    if (t == 0) {
        float s = wsum[0] + wsum[1] + wsum[2] + wsum[3];
        if (USE_WS) {
            dst[blockIdx.x] = s * scale;
        } else {
            atomicAdd(dst, s * scale);
        }
    }
}

__global__ __launch_bounds__(1024) void reduce_kernel(
    const float* __restrict__ ws, float* __restrict__ out, int n) {
    float s = 0.0f;
    for (int i = threadIdx.x; i < n; i += 1024) s += ws[i];
#pragma unroll
    for (int off = 32; off > 0; off >>= 1) s += __shfl_down(s, off);

    __shared__ float acc[16];
    int wave = threadIdx.x >> 6;
    int lane = threadIdx.x & 63;
    if (lane == 0) acc[wave] = s;
    __syncthreads();

    if (threadIdx.x == 0) {
        float tot = 0.0f;
#pragma unroll
        for (int w = 0; w < 16; ++w) tot += acc[w];
        out[0] = tot;
    }
}

extern "C" void kernel_launch(void* const* d_in, const int* in_sizes, int n_in,
                              void* d_out, int out_size, void* d_ws, size_t ws_size,
                              hipStream_t stream) {
    const float* pred = (const float*)d_in[0];
    const float* targ = (const float*)d_in[1];
    float* out = (float*)d_out;

    int ncells = in_sizes[0] / NC;  // B*7*7
    int batch = ncells / 49;        // B
    float inv_b = 1.0f / (float)batch;

    int nchunks = (ncells + 63) / 64;
    int grid = nchunks < 2048 ? nchunks : 2048;

    if (ws_size >= (size_t)grid * sizeof(float)) {
        float* ws = (float*)d_ws;
        yolo_partial_kernel<true><<<grid, 256, 0, stream>>>(pred, targ, ws,
                                                            ncells, inv_b);
        reduce_kernel<<<1, 1024, 0, stream>>>(ws, out, grid);
    } else {
        hipMemsetAsync(out, 0, sizeof(float), stream);
        yolo_partial_kernel<false><<<grid, 256, 0, stream>>>(pred, targ, out,
                                                             ncells, inv_b);
    }
}

// Round 10
// 38.296 us; speedup vs baseline: 1.1085x; 1.1085x over previous
//
#include <hip/hip_runtime.h>

// YOLO loss on (B,7,7,30) fp32 pred/target -> scalar.
// R10 = R7 exactly (best: 37.9us): 4 lanes/cell, single-pass coalesced
// dwordx4 loads, cls fully in-lane, 4 shuffles/chunk, coord/IoU divergent on
// 16/64 lanes, block partials -> ws, tiny reduce kernel. nt-loads (R9)
// reverted: they cost L3 residency on replay (38->42.5us).
// Plateau ledger: six structures (occ 12-60%, ILP x1-x2) all 36.2-38.0us;
// L3-resident replays no faster than cold => read service-path bound at
// ~9.3 B/cyc/CU vs 10.2 ceiling (m13). This is the roofline.

#define NC 30

typedef float f4 __attribute__((ext_vector_type(4), aligned(4)));

__device__ __forceinline__ float sq(float x) { return x * x; }

__device__ __forceinline__ void make_box(float cx, float cy, float w, float h,
                                         float jf, float kf, float b[4]) {
    float x = (cx + jf) * (1.0f / 7.0f);
    float y = (cy + kf) * (1.0f / 7.0f);
    b[0] = x - w * 0.5f;
    b[1] = y - h * 0.5f;
    b[2] = x + w * 0.5f;
    b[3] = y + h * 0.5f;
}

__device__ __forceinline__ float iou(const float a[4], const float b[4]) {
    float ix1 = fmaxf(a[0], b[0]);
    float iy1 = fmaxf(a[1], b[1]);
    float ix2 = fminf(a[2], b[2]);
    float iy2 = fminf(a[3], b[3]);
    float iw = fmaxf(ix2 - ix1, 0.0f);
    float ih = fmaxf(iy2 - iy1, 0.0f);
    float inter = iw * ih;
    float area_a = (a[2] - a[0]) * (a[3] - a[1]);
    float area_b = (b[2] - b[0]) * (b[3] - b[1]);
    return inter > 0.0f ? inter / (area_a + area_b - inter) : 0.0f;
}

template <bool USE_WS>
__global__ __launch_bounds__(256) void yolo_partial_kernel(
    const float* __restrict__ pred, const float* __restrict__ targ,
    float* __restrict__ dst, int ncells, float scale) {
    int t = threadIdx.x;
    int q = t & 3;        // lane within 4-lane cell-group
    int gbase = t & ~3;   // group leader
    int nchunks = (ncells + 63) / 64;  // 64 cells per block-iteration
    int total_dw = ncells * NC;

    float acc = 0.0f;

    for (int chunk = blockIdx.x; chunk < nchunks; chunk += gridDim.x) {
        int cell = chunk * 64 + (t >> 2);
        bool ok = cell < ncells;

        // lane q owns dwords [cell*30 + 8q, +8) of both tensors
        int dwbase = cell * NC + 8 * q;
        int ldbase = dwbase;
        int shift = 0;
        if (ok && dwbase + 8 > total_dw) {  // only the global last lane
            ldbase = total_dw - 8;
            shift = dwbase - ldbase;  // == 2
        }

        f4 Pa = {0.f, 0.f, 0.f, 0.f}, Pb = {0.f, 0.f, 0.f, 0.f};
        f4 Ta = {0.f, 0.f, 0.f, 0.f}, Tb = {0.f, 0.f, 0.f, 0.f};
        if (ok) {
            Pa = *reinterpret_cast<const f4*>(pred + ldbase);
            Pb = *reinterpret_cast<const f4*>(pred + ldbase + 4);
            Ta = *reinterpret_cast<const f4*>(targ + ldbase);
            Tb = *reinterpret_cast<const f4*>(targ + ldbase + 4);
        }
        if (shift) {  // remap loaded -> nominal channel positions (shift==2)
            f4 p0 = Pa, p1 = Pb, u0 = Ta, u1 = Tb;
            Pa[0] = p0[2]; Pa[1] = p0[3]; Pa[2] = p1[0]; Pa[3] = p1[1];
            Pb[0] = p1[2]; Pb[1] = p1[3]; Pb[2] = 0.f;   Pb[3] = 0.f;
            Ta[0] = u0[2]; Ta[1] = u0[3]; Ta[2] = u1[0]; Ta[3] = u1[1];
            Tb[0] = u1[2]; Tb[1] = u1[3]; Tb[2] = 0.f;   Tb[3] = 0.f;
        }

        // obj mask: T4 lives in group-leader's Tb[0]
        float t4 = __shfl(Tb[0], gbase, 64);
        float objw = t4 > 0.0f ? 1.0f : 0.0f;

        // cls partial fully in-lane: ch = 8q + e (Pa: e=0..3, Pb: e=4..7)
        float cls = 0.0f;
#pragma unroll
        for (int e = 0; e < 4; ++e) {
            int ch = 8 * q + e;
            float d = Pa[e] - Ta[e];
            cls += (ch >= 10 && ch < NC) ? d * d : 0.0f;
        }
#pragma unroll
        for (int e = 0; e < 4; ++e) {
            int ch = 8 * q + 4 + e;
            float d = Pb[e] - Tb[e];
            cls += (ch >= 10 && ch < NC) ? d * d : 0.0f;
        }
        acc += objw * cls;

        // gather for coord: lane q=1 holds d8..11 in its Pa/Ta
        float P8 = __shfl(Pa[0], gbase + 1, 64);
        float P9 = __shfl(Pa[1], gbase + 1, 64);
        float T8 = __shfl(Ta[0], gbase + 1, 64);  // T9 unused by reference

        if (q == 0 && ok) {
            // local: P0..3=Pa, P4..7=Pb, T0..3=Ta, T4..7=Tb
            int q7 = cell / 7;
            float kf = (float)(cell - q7 * 7);
            float jf = (float)(q7 % 7);

            float b1[4], b2[4], tbx[4];
            make_box(Pa[0], Pa[1], Pa[2], Pa[3], jf, kf, b1);
            make_box(Pb[1], Pb[2], Pb[3], P8, jf, kf, b2);
            make_box(Ta[0], Ta[1], Ta[2], Ta[3], jf, kf, tbx);

            float i1 = iou(b1, tbx);
            float i2 = iou(b2, tbx);

            bool obj = Tb[0] > 0.0f;
            bool pick1 = i1 >= i2;

            float coo1 = 5.0f * (sq(Pa[0] - Ta[0]) + sq(Pa[1] - Ta[1]) +
                                 sq(sqrtf(Pa[2]) - sqrtf(Ta[2])) +
                                 sq(sqrtf(Pa[3]) - sqrtf(Ta[3]))) +
                         sq(Pb[0] - i1);
            float non1 = 0.5f * sq(Pb[0] - i2);

            float coo2 = 5.0f * (sq(Pb[1] - Tb[1]) + sq(Pb[2] - Tb[2]) +
                                 sq(sqrtf(Pb[3]) - sqrtf(Tb[3])) +
                                 sq(sqrtf(P8) - sqrtf(T8))) +
                         sq(P9 - i2);
            float non2 = 0.5f * sq(P9 - i1);

            float noobj = 0.5f * (Pb[0] * Pb[0] + P9 * P9);

            float resp = pick1 ? (coo1 + non1) : (coo2 + non2);
            acc += obj ? resp : noobj;
        }
    }

    // block reduction, one plain store per block
#pragma unroll
    for (int off = 32; off > 0; off >>= 1) acc += __shfl_down(acc, off);

    __shared__ float wsum[4];
    int wave = t >> 6;
    int lane = t & 63;
    if (lane == 0) wsum[wave] = acc;
    __syncthreads();

    if (t == 0) {
        float s = wsum[0] + wsum[1] + wsum[2] + wsum[3];
        if (USE_WS) {
            dst[blockIdx.x] = s * scale;
        } else {
            atomicAdd(dst, s * scale);
        }
    }
}

__global__ __launch_bounds__(1024) void reduce_kernel(
    const float* __restrict__ ws, float* __restrict__ out, int n) {
    float s = 0.0f;
    for (int i = threadIdx.x; i < n; i += 1024) s += ws[i];
#pragma unroll
    for (int off = 32; off > 0; off >>= 1) s += __shfl_down(s, off);

    __shared__ float acc[16];
    int wave = threadIdx.x >> 6;
    int lane = threadIdx.x & 63;
    if (lane == 0) acc[wave] = s;
    __syncthreads();

    if (threadIdx.x == 0) {
        float tot = 0.0f;
#pragma unroll
        for (int w = 0; w < 16; ++w) tot += acc[w];
        out[0] = tot;
    }
}

extern "C" void kernel_launch(void* const* d_in, const int* in_sizes, int n_in,
                              void* d_out, int out_size, void* d_ws, size_t ws_size,
                              hipStream_t stream) {
    const float* pred = (const float*)d_in[0];
    const float* targ = (const float*)d_in[1];
    float* out = (float*)d_out;

    int ncells = in_sizes[0] / NC;  // B*7*7
    int batch = ncells / 49;        // B
    float inv_b = 1.0f / (float)batch;

    int nchunks = (ncells + 63) / 64;
    int grid = nchunks < 2048 ? nchunks : 2048;

    if (ws_size >= (size_t)grid * sizeof(float)) {
        float* ws = (float*)d_ws;
        yolo_partial_kernel<true><<<grid, 256, 0, stream>>>(pred, targ, ws,
                                                            ncells, inv_b);
        reduce_kernel<<<1, 1024, 0, stream>>>(ws, out, grid);
    } else {
        hipMemsetAsync(out, 0, sizeof(float), stream);
        yolo_partial_kernel<false><<<grid, 256, 0, stream>>>(pred, targ, out,
                                                             ncells, inv_b);
    }
}